// Round 1
// baseline (998.515 us; speedup 1.0000x reference)
//
#include <hip/hip_runtime.h>

#define F 128            // feature dim (HID == NF == 128)
#define LOG2F_ 0.69314718055994530942f

typedef __attribute__((ext_vector_type(8))) __bf16 bf16x8;
typedef __attribute__((ext_vector_type(4))) float floatx4;

__device__ __forceinline__ float ssp(float x) {
    // softplus(x) - log(2), numerically stable
    return fmaxf(x, 0.0f) + log1pf(__expf(-fabsf(x))) - LOG2F_;
}

// ---------------------------------------------------------------------------
// prep: convert weights f32 -> bf16 (hi) and residual (lo) where split needed
// ---------------------------------------------------------------------------
__global__ void prep_kernel(const float* __restrict__ fc1w,
                            const float* __restrict__ fw1,
                            const float* __restrict__ fw2,
                            const float* __restrict__ sw1,
                            const float* __restrict__ sw2,
                            __bf16* __restrict__ fc1h, __bf16* __restrict__ fc1l,
                            __bf16* __restrict__ fw1h, __bf16* __restrict__ fw2h,
                            __bf16* __restrict__ sw1h, __bf16* __restrict__ sw1l,
                            __bf16* __restrict__ sw2h, __bf16* __restrict__ sw2l)
{
    int i = blockIdx.x * blockDim.x + threadIdx.x;
    if (i >= F * F) return;
    float v; __bf16 h;
    v = fc1w[i]; h = (__bf16)v; fc1h[i] = h; fc1l[i] = (__bf16)(v - (float)h);
    v = sw1[i];  h = (__bf16)v; sw1h[i] = h; sw1l[i] = (__bf16)(v - (float)h);
    v = sw2[i];  h = (__bf16)v; sw2h[i] = h; sw2l[i] = (__bf16)(v - (float)h);
    fw1h[i] = (__bf16)fw1[i];
    fw2h[i] = (__bf16)fw2[i];
}

// ---------------------------------------------------------------------------
// y = x @ fc1_w.T   (split bf16, 3-term MFMA -> ~f32 exact)
// block = 256 thr (4 waves), 64 rows/block, wave w owns rows [16w,16w+16)
// ---------------------------------------------------------------------------
__global__ __launch_bounds__(256) void fc1_kernel(
    const float* __restrict__ x, const __bf16* __restrict__ wh,
    const __bf16* __restrict__ wl, float* __restrict__ y, int M)
{
    const int tid = threadIdx.x;
    const int wv = tid >> 6, lane = tid & 63;
    const int m16 = lane & 15, q = lane >> 4;
    const int rowA0 = blockIdx.x * 64 + wv * 16 + m16;
    const int rowA = rowA0 < M ? rowA0 : M - 1;

    floatx4 acc[8] = {};
    #pragma unroll
    for (int ks = 0; ks < 4; ++ks) {
        const int kb = ks * 32 + q * 8;
        const float4* p = (const float4*)(x + (size_t)rowA * F + kb);
        float4 a0 = p[0], a1 = p[1];
        float fv[8] = {a0.x, a0.y, a0.z, a0.w, a1.x, a1.y, a1.z, a1.w};
        bf16x8 ah, al;
        #pragma unroll
        for (int i = 0; i < 8; ++i) {
            __bf16 h = (__bf16)fv[i];
            ah[i] = h; al[i] = (__bf16)(fv[i] - (float)h);
        }
        #pragma unroll
        for (int nt = 0; nt < 8; ++nt) {
            const size_t wo = (size_t)(nt * 16 + m16) * F + kb;
            bf16x8 bh = *(const bf16x8*)(wh + wo);
            bf16x8 bl = *(const bf16x8*)(wl + wo);
            acc[nt] = __builtin_amdgcn_mfma_f32_16x16x32_bf16(ah, bh, acc[nt], 0, 0, 0);
            acc[nt] = __builtin_amdgcn_mfma_f32_16x16x32_bf16(al, bh, acc[nt], 0, 0, 0);
            acc[nt] = __builtin_amdgcn_mfma_f32_16x16x32_bf16(ah, bl, acc[nt], 0, 0, 0);
        }
    }
    const int rowD0 = blockIdx.x * 64 + wv * 16 + q * 4;
    #pragma unroll
    for (int nt = 0; nt < 8; ++nt) {
        const int col = nt * 16 + m16;
        #pragma unroll
        for (int r = 0; r < 4; ++r) {
            const int row = rowD0 + r;
            if (row < M) y[(size_t)row * F + col] = acc[nt][r];
        }
    }
}

// ---------------------------------------------------------------------------
// Edge kernel: W = ssp(ssp(ea@f_w1.T+b1)@f_w2.T+b2); scatter y[src]*W -> agg[dst]
// block = 256 thr, 64 edges/block; pure bf16 filter MLP, f32 atomics out.
// ---------------------------------------------------------------------------
__global__ __launch_bounds__(256) void edge_kernel(
    const float* __restrict__ edge_attr,
    const int* __restrict__ eidx,          // [2][E]: row0=src, row1=dst
    const float* __restrict__ fb1, const float* __restrict__ fb2,
    const __bf16* __restrict__ fw1, const __bf16* __restrict__ fw2,
    const float* __restrict__ y,
    float* __restrict__ agg, int E)
{
    __shared__ __bf16 h1[64][136];   // stride 136 = 68 dwords == 4 mod 32 -> conflict-free b128

    const int tid = threadIdx.x;
    const int wv = tid >> 6, lane = tid & 63;
    const int m16 = lane & 15, q = lane >> 4;
    const int e0 = blockIdx.x * 64;
    const int rowA0 = e0 + wv * 16 + m16;
    const int rowA = rowA0 < E ? rowA0 : E - 1;

    // ---- stage 1: h1 = ssp(ea @ f_w1.T + b1) ----
    floatx4 acc[8] = {};
    #pragma unroll
    for (int ks = 0; ks < 4; ++ks) {
        const int kb = ks * 32 + q * 8;
        const float4* pa = (const float4*)(edge_attr + (size_t)rowA * F + kb);
        float4 a0 = pa[0], a1 = pa[1];
        float fv[8] = {a0.x, a0.y, a0.z, a0.w, a1.x, a1.y, a1.z, a1.w};
        bf16x8 aF;
        #pragma unroll
        for (int i = 0; i < 8; ++i) aF[i] = (__bf16)fv[i];
        #pragma unroll
        for (int nt = 0; nt < 8; ++nt) {
            bf16x8 bF = *(const bf16x8*)(fw1 + (size_t)(nt * 16 + m16) * F + kb);
            acc[nt] = __builtin_amdgcn_mfma_f32_16x16x32_bf16(aF, bF, acc[nt], 0, 0, 0);
        }
    }
    #pragma unroll
    for (int nt = 0; nt < 8; ++nt) {
        const int col = nt * 16 + m16;
        const float b = fb1[col];
        #pragma unroll
        for (int r = 0; r < 4; ++r) {
            const int row = wv * 16 + q * 4 + r;
            h1[row][col] = (__bf16)ssp(acc[nt][r] + b);
        }
    }
    __syncthreads();

    // ---- stage 2: W = ssp(h1 @ f_w2.T + b2) ----
    floatx4 zero = {};
    #pragma unroll
    for (int nt = 0; nt < 8; ++nt) acc[nt] = zero;
    #pragma unroll
    for (int ks = 0; ks < 4; ++ks) {
        const int kb = ks * 32 + q * 8;
        bf16x8 aF = *(const bf16x8*)(&h1[wv * 16 + m16][kb]);
        #pragma unroll
        for (int nt = 0; nt < 8; ++nt) {
            bf16x8 bF = *(const bf16x8*)(fw2 + (size_t)(nt * 16 + m16) * F + kb);
            acc[nt] = __builtin_amdgcn_mfma_f32_16x16x32_bf16(aF, bF, acc[nt], 0, 0, 0);
        }
    }

    // ---- stage 3: msg = y[src] * W, atomic scatter to agg[dst] ----
    int src[4], dst[4], ok[4];
    #pragma unroll
    for (int r = 0; r < 4; ++r) {
        const int e = e0 + wv * 16 + q * 4 + r;
        const int ec = e < E ? e : E - 1;
        ok[r] = (e < E);
        src[r] = eidx[ec];
        dst[r] = eidx[E + ec];
    }
    #pragma unroll
    for (int nt = 0; nt < 8; ++nt) {
        const int col = nt * 16 + m16;
        const float b = fb2[col];
        #pragma unroll
        for (int r = 0; r < 4; ++r) {
            if (ok[r]) {
                const float wV = ssp(acc[nt][r] + b);
                const float v = y[(size_t)src[r] * F + col] * wV;
                unsafeAtomicAdd(&agg[(size_t)dst[r] * F + col], v);
            }
        }
    }
}

// ---------------------------------------------------------------------------
// out = ssp(agg @ s_w1.T) @ s_w2.T   (split bf16 both stages -> ~f32 exact)
// ---------------------------------------------------------------------------
__global__ __launch_bounds__(256) void state_kernel(
    const float* __restrict__ agg,
    const __bf16* __restrict__ w1h, const __bf16* __restrict__ w1l,
    const __bf16* __restrict__ w2h, const __bf16* __restrict__ w2l,
    float* __restrict__ out, int M)
{
    __shared__ __bf16 hh[64][136];
    __shared__ __bf16 hl[64][136];

    const int tid = threadIdx.x;
    const int wv = tid >> 6, lane = tid & 63;
    const int m16 = lane & 15, q = lane >> 4;
    const int rowA0 = blockIdx.x * 64 + wv * 16 + m16;
    const int rowA = rowA0 < M ? rowA0 : M - 1;

    floatx4 acc[8] = {};
    #pragma unroll
    for (int ks = 0; ks < 4; ++ks) {
        const int kb = ks * 32 + q * 8;
        const float4* p = (const float4*)(agg + (size_t)rowA * F + kb);
        float4 a0 = p[0], a1 = p[1];
        float fv[8] = {a0.x, a0.y, a0.z, a0.w, a1.x, a1.y, a1.z, a1.w};
        bf16x8 ah, al;
        #pragma unroll
        for (int i = 0; i < 8; ++i) {
            __bf16 h = (__bf16)fv[i];
            ah[i] = h; al[i] = (__bf16)(fv[i] - (float)h);
        }
        #pragma unroll
        for (int nt = 0; nt < 8; ++nt) {
            const size_t wo = (size_t)(nt * 16 + m16) * F + kb;
            bf16x8 bh = *(const bf16x8*)(w1h + wo);
            bf16x8 bl = *(const bf16x8*)(w1l + wo);
            acc[nt] = __builtin_amdgcn_mfma_f32_16x16x32_bf16(ah, bh, acc[nt], 0, 0, 0);
            acc[nt] = __builtin_amdgcn_mfma_f32_16x16x32_bf16(al, bh, acc[nt], 0, 0, 0);
            acc[nt] = __builtin_amdgcn_mfma_f32_16x16x32_bf16(ah, bl, acc[nt], 0, 0, 0);
        }
    }
    #pragma unroll
    for (int nt = 0; nt < 8; ++nt) {
        const int col = nt * 16 + m16;
        #pragma unroll
        for (int r = 0; r < 4; ++r) {
            const int row = wv * 16 + q * 4 + r;
            const float h = ssp(acc[nt][r]);
            const __bf16 H = (__bf16)h;
            hh[row][col] = H;
            hl[row][col] = (__bf16)(h - (float)H);
        }
    }
    __syncthreads();

    floatx4 zero = {};
    #pragma unroll
    for (int nt = 0; nt < 8; ++nt) acc[nt] = zero;
    #pragma unroll
    for (int ks = 0; ks < 4; ++ks) {
        const int kb = ks * 32 + q * 8;
        bf16x8 aH = *(const bf16x8*)(&hh[wv * 16 + m16][kb]);
        bf16x8 aL = *(const bf16x8*)(&hl[wv * 16 + m16][kb]);
        #pragma unroll
        for (int nt = 0; nt < 8; ++nt) {
            const size_t wo = (size_t)(nt * 16 + m16) * F + kb;
            bf16x8 bh = *(const bf16x8*)(w2h + wo);
            bf16x8 bl = *(const bf16x8*)(w2l + wo);
            acc[nt] = __builtin_amdgcn_mfma_f32_16x16x32_bf16(aH, bh, acc[nt], 0, 0, 0);
            acc[nt] = __builtin_amdgcn_mfma_f32_16x16x32_bf16(aL, bh, acc[nt], 0, 0, 0);
            acc[nt] = __builtin_amdgcn_mfma_f32_16x16x32_bf16(aH, bl, acc[nt], 0, 0, 0);
        }
    }
    const int rowD0 = blockIdx.x * 64 + wv * 16 + q * 4;
    #pragma unroll
    for (int nt = 0; nt < 8; ++nt) {
        const int col = nt * 16 + m16;
        #pragma unroll
        for (int r = 0; r < 4; ++r) {
            const int row = rowD0 + r;
            if (row < M) out[(size_t)row * F + col] = acc[nt][r];
        }
    }
}

// ---------------------------------------------------------------------------
extern "C" void kernel_launch(void* const* d_in, const int* in_sizes, int n_in,
                              void* d_out, int out_size, void* d_ws, size_t ws_size,
                              hipStream_t stream)
{
    const float* x         = (const float*)d_in[0];
    const float* edge_attr = (const float*)d_in[1];
    const int*   eidx      = (const int*)d_in[2];
    const float* fc1w      = (const float*)d_in[3];
    const float* fw1       = (const float*)d_in[4];
    const float* fb1       = (const float*)d_in[5];
    const float* fw2       = (const float*)d_in[6];
    const float* fb2       = (const float*)d_in[7];
    const float* sw1       = (const float*)d_in[8];
    const float* sw2       = (const float*)d_in[9];
    float* out = (float*)d_out;

    const int N = in_sizes[0] / F;     // 50000
    const int E = in_sizes[1] / F;     // 600000

    float* agg = (float*)d_ws;
    float* y   = agg + (size_t)N * F;
    __bf16* wb = (__bf16*)(y + (size_t)N * F);
    const int WSZ = F * F;
    __bf16* fc1h = wb;            __bf16* fc1l = wb + WSZ;
    __bf16* fw1h = wb + 2 * WSZ;  __bf16* fw2h = wb + 3 * WSZ;
    __bf16* sw1h = wb + 4 * WSZ;  __bf16* sw1l = wb + 5 * WSZ;
    __bf16* sw2h = wb + 6 * WSZ;  __bf16* sw2l = wb + 7 * WSZ;

    // agg must start at zero (ws is poisoned before every launch)
    hipMemsetAsync(agg, 0, (size_t)N * F * sizeof(float), stream);

    prep_kernel<<<(WSZ + 255) / 256, 256, 0, stream>>>(
        fc1w, fw1, fw2, sw1, sw2, fc1h, fc1l, fw1h, fw2h, sw1h, sw1l, sw2h, sw2l);

    fc1_kernel<<<(N + 63) / 64, 256, 0, stream>>>(x, fc1h, fc1l, y, N);

    edge_kernel<<<(E + 63) / 64, 256, 0, stream>>>(
        edge_attr, eidx, fb1, fb2, fw1h, fw2h, y, agg, E);

    state_kernel<<<(N + 63) / 64, 256, 0, stream>>>(
        agg, sw1h, sw1l, sw2h, sw2l, out, N);
}

// Round 2
// 931.136 us; speedup vs baseline: 1.0724x; 1.0724x over previous
//
#include <hip/hip_runtime.h>

#define F 128            // feature dim (HID == NF == 128)

typedef __attribute__((ext_vector_type(8))) __bf16 bf16x8;
typedef __attribute__((ext_vector_type(4))) float floatx4;

// shifted softplus: softplus(x) - log(2) == log((1+e^x)/2)
// hardware transcendentals only (v_exp_f32 / v_log_f32), ~1e-7 abs error
__device__ __forceinline__ float ssp(float x) {
    return __logf(fmaf(0.5f, __expf(x), 0.5f));
}

// ---------------------------------------------------------------------------
// prep: convert weights f32 -> bf16 (hi) and residual (lo) where split needed
// ---------------------------------------------------------------------------
__global__ void prep_kernel(const float* __restrict__ fc1w,
                            const float* __restrict__ fw1,
                            const float* __restrict__ fw2,
                            const float* __restrict__ sw1,
                            const float* __restrict__ sw2,
                            __bf16* __restrict__ fc1h, __bf16* __restrict__ fc1l,
                            __bf16* __restrict__ fw1h, __bf16* __restrict__ fw2h,
                            __bf16* __restrict__ sw1h, __bf16* __restrict__ sw1l,
                            __bf16* __restrict__ sw2h, __bf16* __restrict__ sw2l)
{
    int i = blockIdx.x * blockDim.x + threadIdx.x;
    if (i >= F * F) return;
    float v; __bf16 h;
    v = fc1w[i]; h = (__bf16)v; fc1h[i] = h; fc1l[i] = (__bf16)(v - (float)h);
    v = sw1[i];  h = (__bf16)v; sw1h[i] = h; sw1l[i] = (__bf16)(v - (float)h);
    v = sw2[i];  h = (__bf16)v; sw2h[i] = h; sw2l[i] = (__bf16)(v - (float)h);
    fw1h[i] = (__bf16)fw1[i];
    fw2h[i] = (__bf16)fw2[i];
}

// ---------------------------------------------------------------------------
// y = x @ fc1_w.T   (split bf16, 3-term MFMA -> ~f32 exact)
// block = 256 thr (4 waves), 32 rows/block; wave (g,c) owns rows [16g,16g+16)
// x cols [64c, 64c+64).  grid = ceil(M/32) -> ~6 waves/SIMD for latency hiding
// ---------------------------------------------------------------------------
__global__ __launch_bounds__(256) void fc1_kernel(
    const float* __restrict__ x, const __bf16* __restrict__ wh,
    const __bf16* __restrict__ wl, float* __restrict__ y, int M)
{
    const int tid = threadIdx.x;
    const int wv = tid >> 6, lane = tid & 63;
    const int m16 = lane & 15, q = lane >> 4;
    const int g = wv & 1, c = wv >> 1;
    const int rowA0 = blockIdx.x * 32 + g * 16 + m16;
    const int rowA = rowA0 < M ? rowA0 : M - 1;

    floatx4 acc[4] = {};
    #pragma unroll
    for (int ks = 0; ks < 4; ++ks) {
        const int kb = ks * 32 + q * 8;
        const float4* p = (const float4*)(x + (size_t)rowA * F + kb);
        float4 a0 = p[0], a1 = p[1];
        float fv[8] = {a0.x, a0.y, a0.z, a0.w, a1.x, a1.y, a1.z, a1.w};
        bf16x8 ah, al;
        #pragma unroll
        for (int i = 0; i < 8; ++i) {
            __bf16 h = (__bf16)fv[i];
            ah[i] = h; al[i] = (__bf16)(fv[i] - (float)h);
        }
        #pragma unroll
        for (int nt = 0; nt < 4; ++nt) {
            const size_t wo = (size_t)(c * 64 + nt * 16 + m16) * F + kb;
            bf16x8 bh = *(const bf16x8*)(wh + wo);
            bf16x8 bl = *(const bf16x8*)(wl + wo);
            acc[nt] = __builtin_amdgcn_mfma_f32_16x16x32_bf16(ah, bh, acc[nt], 0, 0, 0);
            acc[nt] = __builtin_amdgcn_mfma_f32_16x16x32_bf16(al, bh, acc[nt], 0, 0, 0);
            acc[nt] = __builtin_amdgcn_mfma_f32_16x16x32_bf16(ah, bl, acc[nt], 0, 0, 0);
        }
    }
    const int rowD0 = blockIdx.x * 32 + g * 16 + q * 4;
    #pragma unroll
    for (int nt = 0; nt < 4; ++nt) {
        const int col = c * 64 + nt * 16 + m16;
        #pragma unroll
        for (int r = 0; r < 4; ++r) {
            const int row = rowD0 + r;
            if (row < M) y[(size_t)row * F + col] = acc[nt][r];
        }
    }
}

// ---------------------------------------------------------------------------
// Edge kernel: W = ssp(ssp(ea@f_w1.T+b1)@f_w2.T+b2); scatter y[src]*W -> agg[dst]
// block = 256 thr, 64 edges/block; pure bf16 filter MLP, f32 atomics out.
// ---------------------------------------------------------------------------
__global__ __launch_bounds__(256) void edge_kernel(
    const float* __restrict__ edge_attr,
    const int* __restrict__ eidx,          // [2][E]: row0=src, row1=dst
    const float* __restrict__ fb1, const float* __restrict__ fb2,
    const __bf16* __restrict__ fw1, const __bf16* __restrict__ fw2,
    const float* __restrict__ y,
    float* __restrict__ agg, int E)
{
    __shared__ __bf16 h1[64][136];   // stride 136 = 68 dwords == 4 mod 32 -> conflict-free b128

    const int tid = threadIdx.x;
    const int wv = tid >> 6, lane = tid & 63;
    const int m16 = lane & 15, q = lane >> 4;
    const int e0 = blockIdx.x * 64;
    const int rowA0 = e0 + wv * 16 + m16;
    const int rowA = rowA0 < E ? rowA0 : E - 1;

    // ---- stage 1: h1 = ssp(ea @ f_w1.T + b1) ----
    floatx4 acc[8] = {};
    #pragma unroll
    for (int ks = 0; ks < 4; ++ks) {
        const int kb = ks * 32 + q * 8;
        const float4* pa = (const float4*)(edge_attr + (size_t)rowA * F + kb);
        float4 a0 = pa[0], a1 = pa[1];
        float fv[8] = {a0.x, a0.y, a0.z, a0.w, a1.x, a1.y, a1.z, a1.w};
        bf16x8 aF;
        #pragma unroll
        for (int i = 0; i < 8; ++i) aF[i] = (__bf16)fv[i];
        #pragma unroll
        for (int nt = 0; nt < 8; ++nt) {
            bf16x8 bF = *(const bf16x8*)(fw1 + (size_t)(nt * 16 + m16) * F + kb);
            acc[nt] = __builtin_amdgcn_mfma_f32_16x16x32_bf16(aF, bF, acc[nt], 0, 0, 0);
        }
    }
    #pragma unroll
    for (int nt = 0; nt < 8; ++nt) {
        const int col = nt * 16 + m16;
        const float b = fb1[col];
        #pragma unroll
        for (int r = 0; r < 4; ++r) {
            const int row = wv * 16 + q * 4 + r;
            h1[row][col] = (__bf16)ssp(acc[nt][r] + b);
        }
    }
    __syncthreads();

    // ---- stage 2: W = ssp(h1 @ f_w2.T + b2) ----
    floatx4 zero = {};
    #pragma unroll
    for (int nt = 0; nt < 8; ++nt) acc[nt] = zero;
    #pragma unroll
    for (int ks = 0; ks < 4; ++ks) {
        const int kb = ks * 32 + q * 8;
        bf16x8 aF = *(const bf16x8*)(&h1[wv * 16 + m16][kb]);
        #pragma unroll
        for (int nt = 0; nt < 8; ++nt) {
            bf16x8 bF = *(const bf16x8*)(fw2 + (size_t)(nt * 16 + m16) * F + kb);
            acc[nt] = __builtin_amdgcn_mfma_f32_16x16x32_bf16(aF, bF, acc[nt], 0, 0, 0);
        }
    }

    // ---- stage 3: msg = y[src] * W, atomic scatter to agg[dst] ----
    int src[4], dst[4], ok[4];
    #pragma unroll
    for (int r = 0; r < 4; ++r) {
        const int e = e0 + wv * 16 + q * 4 + r;
        const int ec = e < E ? e : E - 1;
        ok[r] = (e < E);
        src[r] = eidx[ec];
        dst[r] = eidx[E + ec];
    }
    #pragma unroll
    for (int nt = 0; nt < 8; ++nt) {
        const int col = nt * 16 + m16;
        const float b = fb2[col];
        #pragma unroll
        for (int r = 0; r < 4; ++r) {
            if (ok[r]) {
                const float wV = ssp(acc[nt][r] + b);
                const float v = y[(size_t)src[r] * F + col] * wV;
                unsafeAtomicAdd(&agg[(size_t)dst[r] * F + col], v);
            }
        }
    }
}

// ---------------------------------------------------------------------------
// out = ssp(agg @ s_w1.T) @ s_w2.T   (split bf16 both stages -> ~f32 exact)
// block = 256 thr, 32 rows/block; wave (g,c) quadrant layout like fc1.
// ---------------------------------------------------------------------------
__global__ __launch_bounds__(256) void state_kernel(
    const float* __restrict__ agg,
    const __bf16* __restrict__ w1h, const __bf16* __restrict__ w1l,
    const __bf16* __restrict__ w2h, const __bf16* __restrict__ w2l,
    float* __restrict__ out, int M)
{
    __shared__ __bf16 hh[32][136];
    __shared__ __bf16 hl[32][136];

    const int tid = threadIdx.x;
    const int wv = tid >> 6, lane = tid & 63;
    const int m16 = lane & 15, q = lane >> 4;
    const int g = wv & 1, c = wv >> 1;
    const int rowA0 = blockIdx.x * 32 + g * 16 + m16;
    const int rowA = rowA0 < M ? rowA0 : M - 1;

    // stage 1: h = ssp(agg @ s_w1.T), this wave computes cols [64c, 64c+64)
    floatx4 acc[4] = {};
    #pragma unroll
    for (int ks = 0; ks < 4; ++ks) {
        const int kb = ks * 32 + q * 8;
        const float4* p = (const float4*)(agg + (size_t)rowA * F + kb);
        float4 a0 = p[0], a1 = p[1];
        float fv[8] = {a0.x, a0.y, a0.z, a0.w, a1.x, a1.y, a1.z, a1.w};
        bf16x8 ah, al;
        #pragma unroll
        for (int i = 0; i < 8; ++i) {
            __bf16 h = (__bf16)fv[i];
            ah[i] = h; al[i] = (__bf16)(fv[i] - (float)h);
        }
        #pragma unroll
        for (int nt = 0; nt < 4; ++nt) {
            const size_t wo = (size_t)(c * 64 + nt * 16 + m16) * F + kb;
            bf16x8 bh = *(const bf16x8*)(w1h + wo);
            bf16x8 bl = *(const bf16x8*)(w1l + wo);
            acc[nt] = __builtin_amdgcn_mfma_f32_16x16x32_bf16(ah, bh, acc[nt], 0, 0, 0);
            acc[nt] = __builtin_amdgcn_mfma_f32_16x16x32_bf16(al, bh, acc[nt], 0, 0, 0);
            acc[nt] = __builtin_amdgcn_mfma_f32_16x16x32_bf16(ah, bl, acc[nt], 0, 0, 0);
        }
    }
    #pragma unroll
    for (int nt = 0; nt < 4; ++nt) {
        const int col = c * 64 + nt * 16 + m16;
        #pragma unroll
        for (int r = 0; r < 4; ++r) {
            const int row = g * 16 + q * 4 + r;
            const float h = ssp(acc[nt][r]);
            const __bf16 H = (__bf16)h;
            hh[row][col] = H;
            hl[row][col] = (__bf16)(h - (float)H);
        }
    }
    __syncthreads();

    // stage 2: out = h @ s_w2.T, K over all 128 cols of h (written by both c-halves)
    floatx4 zero = {};
    #pragma unroll
    for (int nt = 0; nt < 4; ++nt) acc[nt] = zero;
    #pragma unroll
    for (int ks = 0; ks < 4; ++ks) {
        const int kb = ks * 32 + q * 8;
        bf16x8 aH = *(const bf16x8*)(&hh[g * 16 + m16][kb]);
        bf16x8 aL = *(const bf16x8*)(&hl[g * 16 + m16][kb]);
        #pragma unroll
        for (int nt = 0; nt < 4; ++nt) {
            const size_t wo = (size_t)(c * 64 + nt * 16 + m16) * F + kb;
            bf16x8 bh = *(const bf16x8*)(w2h + wo);
            bf16x8 bl = *(const bf16x8*)(w2l + wo);
            acc[nt] = __builtin_amdgcn_mfma_f32_16x16x32_bf16(aH, bh, acc[nt], 0, 0, 0);
            acc[nt] = __builtin_amdgcn_mfma_f32_16x16x32_bf16(aL, bh, acc[nt], 0, 0, 0);
            acc[nt] = __builtin_amdgcn_mfma_f32_16x16x32_bf16(aH, bl, acc[nt], 0, 0, 0);
        }
    }
    const int rowD0 = blockIdx.x * 32 + g * 16 + q * 4;
    #pragma unroll
    for (int nt = 0; nt < 4; ++nt) {
        const int col = c * 64 + nt * 16 + m16;
        #pragma unroll
        for (int r = 0; r < 4; ++r) {
            const int row = rowD0 + r;
            if (row < M) out[(size_t)row * F + col] = acc[nt][r];
        }
    }
}

// ---------------------------------------------------------------------------
extern "C" void kernel_launch(void* const* d_in, const int* in_sizes, int n_in,
                              void* d_out, int out_size, void* d_ws, size_t ws_size,
                              hipStream_t stream)
{
    const float* x         = (const float*)d_in[0];
    const float* edge_attr = (const float*)d_in[1];
    const int*   eidx      = (const int*)d_in[2];
    const float* fc1w      = (const float*)d_in[3];
    const float* fw1       = (const float*)d_in[4];
    const float* fb1       = (const float*)d_in[5];
    const float* fw2       = (const float*)d_in[6];
    const float* fb2       = (const float*)d_in[7];
    const float* sw1       = (const float*)d_in[8];
    const float* sw2       = (const float*)d_in[9];
    float* out = (float*)d_out;

    const int N = in_sizes[0] / F;     // 50000
    const int E = in_sizes[1] / F;     // 600000

    float* agg = (float*)d_ws;
    float* y   = agg + (size_t)N * F;
    __bf16* wb = (__bf16*)(y + (size_t)N * F);
    const int WSZ = F * F;
    __bf16* fc1h = wb;            __bf16* fc1l = wb + WSZ;
    __bf16* fw1h = wb + 2 * WSZ;  __bf16* fw2h = wb + 3 * WSZ;
    __bf16* sw1h = wb + 4 * WSZ;  __bf16* sw1l = wb + 5 * WSZ;
    __bf16* sw2h = wb + 6 * WSZ;  __bf16* sw2l = wb + 7 * WSZ;

    // agg must start at zero (ws is poisoned before every launch)
    hipMemsetAsync(agg, 0, (size_t)N * F * sizeof(float), stream);

    prep_kernel<<<(WSZ + 255) / 256, 256, 0, stream>>>(
        fc1w, fw1, fw2, sw1, sw2, fc1h, fc1l, fw1h, fw2h, sw1h, sw1l, sw2h, sw2l);

    fc1_kernel<<<(N + 31) / 32, 256, 0, stream>>>(x, fc1h, fc1l, y, N);

    edge_kernel<<<(E + 63) / 64, 256, 0, stream>>>(
        edge_attr, eidx, fb1, fb2, fw1h, fw2h, y, agg, E);

    state_kernel<<<(N + 31) / 32, 256, 0, stream>>>(
        agg, sw1h, sw1l, sw2h, sw2l, out, N);
}